// Round 4
// baseline (179.023 us; speedup 1.0000x reference)
//
#include <hip/hip_runtime.h>
#include <hip/hip_bf16.h>
#include <math.h>

#define BATCH 8192
#define F 256
#define G 32
#define W 512
#define NCHUNK 132   // 128 spline chunks (2 features x 32 g) + 4 skip chunks (64 k each)

typedef float f32x4 __attribute__((ext_vector_type(4)));
typedef short s16x8 __attribute__((ext_vector_type(8)));
typedef long long i64x2 __attribute__((ext_vector_type(2)));

__device__ __forceinline__ short f2bf(float f) {
  unsigned int u = __builtin_bit_cast(unsigned int, f);
  u += 0x7fffu + ((u >> 16) & 1u);
  return (short)(u >> 16);
}

__device__ __forceinline__ float knotv(int i) {
  int j = i - 3;
  j = j < 0 ? 0 : (j > 29 ? 29 : j);
  return (float)j * (1.0f / 29.0f);
}

__device__ __forceinline__ float fdiv_fast(float a, float b) {
  return a * __builtin_amdgcn_rcpf(b);
}

// ---------------- pre-pass: sigmoid table sgT[f][b] (u16), LDS-transposed ----------------
__global__ __launch_bounds__(256) void sig_build(
    const float* __restrict__ inp, const float* __restrict__ shift,
    const float* __restrict__ lscale, unsigned short* __restrict__ sgT)
{
  __shared__ float T[64][257];
  const int b0 = blockIdx.x * 64;
  const int t = threadIdx.x;
  {
    const int r = t & 63, q = t >> 6;
    const float* src = inp + (size_t)(b0 + r) * F + q * 64;
    #pragma unroll
    for (int i = 0; i < 16; ++i) {
      float4 v = *(const float4*)(src + i * 4);
      T[r][q * 64 + i * 4 + 0] = v.x;
      T[r][q * 64 + i * 4 + 1] = v.y;
      T[r][q * 64 + i * 4 + 2] = v.z;
      T[r][q * 64 + i * 4 + 3] = v.w;
    }
  }
  __syncthreads();
  const int f = t;
  float ls = lscale[f];
  const float sc = fmaxf(ls, 0.0f) + __logf(1.0f + __expf(-fabsf(ls))) + 0.001f;
  const float sh = shift[f];
  unsigned short* dst = sgT + (size_t)f * BATCH + b0;
  #pragma unroll
  for (int r8 = 0; r8 < 8; ++r8) {
    unsigned short h[8];
    #pragma unroll
    for (int j = 0; j < 8; ++j) {
      const float z = (T[r8 * 8 + j][f] - sh) * sc;
      const float sg = 1.0f / (1.0f + __expf(-z));
      h[j] = (unsigned short)fminf(sg * 65536.0f, 65535.0f);
    }
    *(s16x8*)(dst + r8 * 8) = *(s16x8*)h;
  }
}

// ---------------- pre-pass: B (coeffs + skip_w) -> bf16 fragment-major ----------------
// layout: frag id = (((c*4 + nt)*2 + wn)*4 + nf)*2 + kk, within frag: lane*8 shorts
//   w = nt*128 + wn*64 + nf*16 + (lane&15);  k = c*64 + kk*32 + (lane>>4)*8 + j
__global__ __launch_bounds__(256) void bws_build(
    const float* __restrict__ coeffs, const float* __restrict__ skip_w,
    short* __restrict__ Bws)
{
  const int gid = blockIdx.x * 256 + threadIdx.x;   // 0 .. 540671
  const int lane = gid & 63;
  const int kk = (gid >> 6) & 1;
  const int nf = (gid >> 7) & 3;
  const int wn = (gid >> 9) & 1;
  const int nt = (gid >> 10) & 3;
  const int c  = gid >> 12;
  const int w  = nt * 128 + wn * 64 + nf * 16 + (lane & 15);
  const int kl = kk * 32 + (lane >> 4) * 8;
  const float* src = (c < 128) ? (coeffs + (size_t)(c * 64 + kl) * W + w)
                               : (skip_w + (size_t)((c - 128) * 64 + kl) * W + w);
  s16x8 h;
  #pragma unroll
  for (int j = 0; j < 8; ++j) h[j] = f2bf(src[(size_t)j * W]);
  ((s16x8*)Bws)[gid] = h;
}

// ---------------- A staging: spline row (funnel-shift window) or input copy ----------------
__device__ __forceinline__ void stage_a(short* __restrict__ dst, int cc,
    int tid, int m0, const unsigned short* __restrict__ sgT,
    const float* __restrict__ inp)
{
  const int bp = tid & 127;
  const int hi = tid >> 7;              // fi for spline; k-half for skip
  const int wmA = bp >> 6;
  const int mf = (bp >> 4) & 3;
  const int l15b = bp & 15;
  short* base = dst + (((wmA * 4 + mf) * 2 + hi) * 64 + l15b) * 8;  // + lq*128 shorts
  if (cc < 128) {
    const float sg = ((float)sgT[(size_t)(2 * cc + hi) * BATCH + m0 + bp] + 0.5f) * (1.0f / 65536.0f);
    const int s0 = (int)(sg * 29.0f);   // in [0,28]
    const int sp = s0 + 3;
    float Nv[4], lef[4], rig[4];
    Nv[0] = 1.0f;
    #pragma unroll
    for (int r = 1; r <= 3; ++r) {
      lef[r] = sg - knotv(sp + 1 - r);
      rig[r] = knotv(sp + r) - sg;
      float saved = 0.0f;
      #pragma unroll
      for (int j = 0; j < r; ++j) {
        float temp = fdiv_fast(Nv[j], rig[j + 1] + lef[r - j]);
        Nv[j] = saved + rig[j + 1] * temp;
        saved = lef[r - j] * temp;
      }
      Nv[r] = saved;
    }
    unsigned long long nv =
        (unsigned long long)(unsigned short)f2bf(Nv[0])
      | ((unsigned long long)(unsigned short)f2bf(Nv[1]) << 16)
      | ((unsigned long long)(unsigned short)f2bf(Nv[2]) << 32)
      | ((unsigned long long)(unsigned short)f2bf(Nv[3]) << 48);
    const int p = s0 & 7, ga = s0 >> 3;
    const int s = 16 * p, shl = s & 63;
    const unsigned long long a = nv << shl;
    const unsigned long long b = (nv >> (63 - shl)) >> 1;
    const bool hs = (s >= 64);
    i64x2 d0, d1, z;
    d0[0] = hs ? 0ll : (long long)a;
    d0[1] = hs ? (long long)a : (long long)b;
    d1[0] = hs ? (long long)b : 0ll;
    d1[1] = 0ll;
    z[0] = 0ll; z[1] = 0ll;
    *(i64x2*)(base + ga * 128) = d0;
    *(i64x2*)(base + ((ga + 1) & 3) * 128) = d1;
    *(i64x2*)(base + ((ga + 2) & 3) * 128) = z;
    *(i64x2*)(base + ((ga + 3) & 3) * 128) = z;
  } else {
    const int sb = (cc - 128) * 64 + hi * 32;
    const float* ip = inp + (size_t)(m0 + bp) * F + sb;
    #pragma unroll
    for (int lq = 0; lq < 4; ++lq) {
      s16x8 h;
      #pragma unroll
      for (int j = 0; j < 8; ++j) h[j] = f2bf(ip[lq * 8 + j]);
      *(s16x8*)(base + lq * 128) = h;
    }
  }
}

// ---------------- main GEMM: 4 waves, 64x64 wave tiles, B global->reg ----------------
__global__ __launch_bounds__(256, 1) void kan_gemm_v4(
    const float* __restrict__ inp, const unsigned short* __restrict__ sgT,
    const short* __restrict__ Bws,
    const float* __restrict__ bias, const float* __restrict__ skip_b,
    float* __restrict__ out)
{
  __shared__ short Abuf0[8192];
  __shared__ short Abuf1[8192];

  const int tid = threadIdx.x;
  const int lane = tid & 63;
  const int wid = tid >> 6;
  const int wm = wid >> 1, wn = wid & 1;

  // XCD-bijective swizzle (256 = 8*32)
  const int nb = (blockIdx.x & 7) * 32 + (blockIdx.x >> 3);
  const int mt = nb >> 2, nt = nb & 3;
  const int m0 = mt * 128, n0 = nt * 128;

  f32x4 acc[4][4];
  #pragma unroll
  for (int i = 0; i < 4; ++i)
    #pragma unroll
    for (int j = 0; j < 4; ++j)
      acc[i][j] = (f32x4){0.f, 0.f, 0.f, 0.f};

  s16x8 b0[8], b1[8];
  // prologue: B frags for c=0, A tile for c=0
  {
    const s16x8* bsrc = (const s16x8*)(Bws + ((size_t)((0 * 4 + nt) * 2 + wn)) * 4096) + lane;
    #pragma unroll
    for (int q = 0; q < 8; ++q) b0[q] = bsrc[q * 64];
  }
  stage_a(Abuf0, 0, tid, m0, sgT, inp);

#define CHUNK(ACUR, ANXT, BCUR, BNXT, C_) do {                                  \
    const int c_ = (C_);                                                        \
    asm volatile("s_waitcnt lgkmcnt(0)" ::: "memory");                          \
    __builtin_amdgcn_s_barrier();                                               \
    if (c_ + 1 < NCHUNK) {                                                      \
      const s16x8* bsrc = (const s16x8*)(Bws +                                  \
          ((size_t)(((c_ + 1) * 4 + nt) * 2 + wn)) * 4096) + lane;              \
      _Pragma("unroll")                                                         \
      for (int q = 0; q < 8; ++q) BNXT[q] = bsrc[q * 64];                       \
      stage_a(ANXT, c_ + 1, tid, m0, sgT, inp);                                 \
    }                                                                           \
    s16x8 af[8];                                                                \
    _Pragma("unroll")                                                           \
    for (int mf = 0; mf < 4; ++mf)                                              \
      _Pragma("unroll")                                                         \
      for (int kk = 0; kk < 2; ++kk)                                            \
        af[mf * 2 + kk] =                                                       \
            *(const s16x8*)&ACUR[(((wm * 4 + mf) * 2 + kk) * 64 + lane) * 8];   \
    _Pragma("unroll")                                                           \
    for (int kk = 0; kk < 2; ++kk)                                              \
      _Pragma("unroll")                                                         \
      for (int mf = 0; mf < 4; ++mf)                                            \
        _Pragma("unroll")                                                       \
        for (int nf = 0; nf < 4; ++nf)                                          \
          acc[mf][nf] = __builtin_amdgcn_mfma_f32_16x16x32_bf16(                \
              af[mf * 2 + kk], BCUR[nf * 2 + kk], acc[mf][nf], 0, 0, 0);        \
  } while (0)

  for (int c = 0; c < NCHUNK; c += 2) {
    CHUNK(Abuf0, Abuf1, b0, b1, c);
    CHUNK(Abuf1, Abuf0, b1, b0, c + 1);
  }
#undef CHUNK

  // ---------- epilogue ----------
  const int l15 = lane & 15;
  const int lq = lane >> 4;
  #pragma unroll
  for (int nf = 0; nf < 4; ++nf) {
    const int col = n0 + wn * 64 + nf * 16 + l15;
    const float badd = bias[col] + skip_b[col];
    #pragma unroll
    for (int mf = 0; mf < 4; ++mf) {
      const int r0 = m0 + wm * 64 + mf * 16 + lq * 4;
      #pragma unroll
      for (int r = 0; r < 4; ++r)
        out[(size_t)(r0 + r) * W + col] = acc[mf][nf][r] + badd;
    }
  }
}

// ---------------- fallback GEMM (no ws) — round-2 kernel ----------------
__device__ __forceinline__ void issue_b(int c, int uu, int n0,
                                        const float* __restrict__ coeffs,
                                        const float* __restrict__ skip_w,
                                        float (&r)[4][8]) {
  const float* base = (c < 128) ? (coeffs + (size_t)c * 64 * W)
                                : (skip_w + (size_t)(c - 128) * 64 * W);
  const int kk = (uu >> 6) & 1;
  const int lq = (uu >> 4) & 3;
  const int l15 = uu & 15;
  const int u7 = uu >> 7;
  #pragma unroll
  for (int s = 0; s < 4; ++s) {
    const int w = (2 * s + u7) * 16 + l15;
    const float* p = base + (size_t)(kk * 32 + lq * 8) * W + n0 + w;
    #pragma unroll
    for (int j = 0; j < 8; ++j) r[s][j] = p[(size_t)j * W];
  }
}

__global__ __launch_bounds__(512, 1) void kan_gemm_v2(
    const float* __restrict__ inp, const float* __restrict__ shift,
    const float* __restrict__ lscale, const float* __restrict__ coeffs,
    const float* __restrict__ bias, const float* __restrict__ skip_w,
    const float* __restrict__ skip_b, float* __restrict__ out)
{
  __shared__ short Abuf[2][8192];
  __shared__ short Bbuf[2][8192];
  __shared__ unsigned short sgl[F * 128];

  const int tid = threadIdx.x;
  const int lane = tid & 63;
  const int wid = tid >> 6;
  const int nb = (blockIdx.x & 7) * 32 + (blockIdx.x >> 3);
  const int mt = nb >> 2;
  const int nt = nb & 3;
  const int m0 = mt * 128;
  const int n0 = nt * 128;

  float bpref[4][8];
  if (tid >= 256) issue_b(0, tid - 256, n0, coeffs, skip_w, bpref);

  float* shf = (float*)&Abuf[0][0];
  if (tid < 256) {
    float ls = lscale[tid];
    shf[tid] = fmaxf(ls, 0.0f) + __logf(1.0f + __expf(-fabsf(ls))) + 0.001f;
    shf[256 + tid] = shift[tid];
  }
  __syncthreads();

  {
    const int row = tid & 127;
    const int q = tid >> 7;
    const float* ip = inp + (size_t)(m0 + row) * F + q * 64;
    #pragma unroll
    for (int i = 0; i < 16; ++i) {
      float4 v = *(const float4*)(ip + i * 4);
      float vv[4] = {v.x, v.y, v.z, v.w};
      #pragma unroll
      for (int j = 0; j < 4; ++j) {
        const int f = q * 64 + i * 4 + j;
        const float z = (vv[j] - shf[256 + f]) * shf[f];
        const float sg = 1.0f / (1.0f + __expf(-z));
        sgl[f * 128 + row] = (unsigned short)fminf(sg * 65536.0f, 65535.0f);
      }
    }
  }
  __syncthreads();

  const int wm = wid >> 2;
  const int wn = wid & 3;

  f32x4 acc[4][2];
  #pragma unroll
  for (int i = 0; i < 4; ++i)
    #pragma unroll
    for (int j = 0; j < 2; ++j)
      acc[i][j] = (f32x4){0.f, 0.f, 0.f, 0.f};

  for (int c = 0; c < NCHUNK; ++c) {
    short* Ab = Abuf[c & 1];
    short* Bb = Bbuf[c & 1];

    if (c < 128) {
      s16x8 z = {0, 0, 0, 0, 0, 0, 0, 0};
      ((s16x8*)Ab)[tid * 2] = z;
      ((s16x8*)Ab)[tid * 2 + 1] = z;
    } else if (tid < 256) {
      const int bp = tid & 127, fi = tid >> 7;
      const int sb = (c - 128) * 64 + fi * 32;
      const float* ip = inp + (size_t)(m0 + bp) * F + sb;
      const int rg = bp >> 4, l15b = bp & 15;
      #pragma unroll
      for (int lq2 = 0; lq2 < 4; ++lq2) {
        s16x8 h;
        #pragma unroll
        for (int j = 0; j < 8; ++j) h[j] = f2bf(ip[lq2 * 8 + j]);
        *(s16x8*)&Ab[((rg * 2 + fi) * 64 + lq2 * 16 + l15b) * 8] = h;
      }
    }
    if (tid >= 256) {
      const int uu = tid - 256;
      #pragma unroll
      for (int s = 0; s < 4; ++s) {
        s16x8 h;
        #pragma unroll
        for (int j = 0; j < 8; ++j) h[j] = f2bf(bpref[s][j]);
        *(s16x8*)&Bb[(s * 256 + uu) * 8] = h;
      }
      if (c + 1 < NCHUNK) issue_b(c + 1, uu, n0, coeffs, skip_w, bpref);
    }
    __syncthreads();

    if (c < 128 && tid < 256) {
      const int bp = tid & 127, fi = tid >> 7;
      const int f = 2 * c + fi;
      const float sg = ((float)sgl[f * 128 + bp] + 0.5f) * (1.0f / 65536.0f);
      int s0 = (int)floorf(sg * 29.0f);
      s0 = s0 < 0 ? 0 : (s0 > 28 ? 28 : s0);
      const int sp = s0 + 3;
      float Nv[4], lef[4], rig[4];
      Nv[0] = 1.0f;
      #pragma unroll
      for (int r = 1; r <= 3; ++r) {
        lef[r] = sg - knotv(sp + 1 - r);
        rig[r] = knotv(sp + r) - sg;
        float saved = 0.0f;
        #pragma unroll
        for (int j = 0; j < r; ++j) {
          float temp = fdiv_fast(Nv[j], rig[j + 1] + lef[r - j]);
          Nv[j] = saved + rig[j + 1] * temp;
          saved = lef[r - j] * temp;
        }
        Nv[r] = saved;
      }
      const int rg = bp >> 4, l15b = bp & 15;
      #pragma unroll
      for (int t = 0; t < 4; ++t) {
        const int g = s0 + t;
        Ab[((rg * 2 + fi) * 64 + (g >> 3) * 16 + l15b) * 8 + (g & 7)] = f2bf(Nv[t]);
      }
    }
    s16x8 bfv[2][2];
    #pragma unroll
    for (int nf = 0; nf < 2; ++nf)
      #pragma unroll
      for (int kk = 0; kk < 2; ++kk)
        bfv[nf][kk] = *(const s16x8*)&Bb[(((wn * 2 + nf) * 2 + kk) * 64 + lane) * 8];
    __syncthreads();

    #pragma unroll
    for (int kk = 0; kk < 2; ++kk) {
      #pragma unroll
      for (int mf = 0; mf < 4; ++mf) {
        s16x8 af = *(const s16x8*)&Ab[(((wm * 4 + mf) * 2 + kk) * 64 + lane) * 8];
        #pragma unroll
        for (int nf = 0; nf < 2; ++nf)
          acc[mf][nf] = __builtin_amdgcn_mfma_f32_16x16x32_bf16(af, bfv[nf][kk], acc[mf][nf], 0, 0, 0);
      }
    }
  }

  const int l15 = lane & 15;
  const int lq = lane >> 4;
  #pragma unroll
  for (int nf = 0; nf < 2; ++nf) {
    const int col = n0 + wn * 32 + nf * 16 + l15;
    const float badd = bias[col] + skip_b[col];
    #pragma unroll
    for (int mf = 0; mf < 4; ++mf) {
      const int r0 = m0 + wm * 64 + mf * 16 + lq * 4;
      #pragma unroll
      for (int r = 0; r < 4; ++r)
        out[(size_t)(r0 + r) * W + col] = acc[mf][nf][r] + badd;
    }
  }
}

__global__ __launch_bounds__(256, 1) void ln_gelu(
    float* __restrict__ out, const float* __restrict__ gamma,
    const float* __restrict__ beta)
{
  const int lane = threadIdx.x & 63;
  const int wid = threadIdx.x >> 6;
  const int row = blockIdx.x * 4 + wid;
  float* p = out + (size_t)row * W + lane * 8;
  float4 a = *(const float4*)p;
  float4 b = *(const float4*)(p + 4);
  float v[8] = {a.x, a.y, a.z, a.w, b.x, b.y, b.z, b.w};
  float s = 0.f, q = 0.f;
  #pragma unroll
  for (int j = 0; j < 8; ++j) { s += v[j]; q += v[j] * v[j]; }
  #pragma unroll
  for (int m = 1; m < 64; m <<= 1) {
    s += __shfl_xor(s, m);
    q += __shfl_xor(q, m);
  }
  const float mu = s * (1.0f / 512.0f);
  const float var = q * (1.0f / 512.0f) - mu * mu;
  const float inv = rsqrtf(var + 1e-5f);
  const float4 g0 = *(const float4*)(gamma + lane * 8);
  const float4 g1 = *(const float4*)(gamma + lane * 8 + 4);
  const float4 b0 = *(const float4*)(beta + lane * 8);
  const float4 b1 = *(const float4*)(beta + lane * 8 + 4);
  float gm[8] = {g0.x, g0.y, g0.z, g0.w, g1.x, g1.y, g1.z, g1.w};
  float bt[8] = {b0.x, b0.y, b0.z, b0.w, b1.x, b1.y, b1.z, b1.w};
  float o[8];
  #pragma unroll
  for (int j = 0; j < 8; ++j) {
    float x = (v[j] - mu) * inv * gm[j] + bt[j];
    o[j] = 0.5f * x * (1.0f + erff(x * 0.70710678f));
  }
  float4 w0 = {o[0], o[1], o[2], o[3]};
  float4 w1 = {o[4], o[5], o[6], o[7]};
  *(float4*)p = w0;
  *(float4*)(p + 4) = w1;
}

extern "C" void kernel_launch(void* const* d_in, const int* in_sizes, int n_in,
                              void* d_out, int out_size, void* d_ws, size_t ws_size,
                              hipStream_t stream) {
  (void)in_sizes; (void)n_in; (void)out_size;
  const float* inp    = (const float*)d_in[0];
  const float* shift  = (const float*)d_in[1];
  const float* lscale = (const float*)d_in[2];
  const float* coeffs = (const float*)d_in[3];
  const float* bias   = (const float*)d_in[4];
  const float* skip_w = (const float*)d_in[5];
  const float* skip_b = (const float*)d_in[6];
  const float* gamma  = (const float*)d_in[7];
  const float* beta   = (const float*)d_in[8];
  float* out = (float*)d_out;

  const size_t needB = (size_t)NCHUNK * 4 * 16384;   // 8,650,752
  const size_t needS = (size_t)F * BATCH * 2;        // 4,194,304

  if (ws_size >= needB + needS) {
    short* Bws = (short*)d_ws;
    unsigned short* sgT = (unsigned short*)((char*)d_ws + needB);
    sig_build<<<dim3(BATCH / 64), dim3(256), 0, stream>>>(inp, shift, lscale, sgT);
    bws_build<<<dim3(2112), dim3(256), 0, stream>>>(coeffs, skip_w, Bws);
    kan_gemm_v4<<<dim3(256), dim3(256), 0, stream>>>(
        inp, sgT, Bws, bias, skip_b, out);
  } else {
    kan_gemm_v2<<<dim3(256), dim3(512), 0, stream>>>(
        inp, shift, lscale, coeffs, bias, skip_w, skip_b, out);
  }
  ln_gelu<<<dim3(BATCH / 4), dim3(256), 0, stream>>>(out, gamma, beta);
}

// Round 5
// 154.257 us; speedup vs baseline: 1.1606x; 1.1606x over previous
//
#include <hip/hip_runtime.h>
#include <hip/hip_bf16.h>
#include <math.h>

#define BATCH 8192
#define F 256
#define G 32
#define W 512
#define NCHUNK 132   // 128 spline chunks (2 features x 32 g) + 4 skip chunks (64 k each)

typedef float f32x4 __attribute__((ext_vector_type(4)));
typedef short s16x8 __attribute__((ext_vector_type(8)));
typedef long long i64x2 __attribute__((ext_vector_type(2)));

__device__ __forceinline__ short f2bf(float f) {
  unsigned int u = __builtin_bit_cast(unsigned int, f);
  u += 0x7fffu + ((u >> 16) & 1u);
  return (short)(u >> 16);
}

__device__ __forceinline__ float knotv(int i) {
  int j = i - 3;
  j = j < 0 ? 0 : (j > 29 ? 29 : j);
  return (float)j * (1.0f / 29.0f);
}

__device__ __forceinline__ float fdiv_fast(float a, float b) {
  return a * __builtin_amdgcn_rcpf(b);
}

// ---------------- pre-pass: sigmoid table sgT[f][b] (u16), LDS-transposed ----------------
__global__ __launch_bounds__(256) void sig_build(
    const float* __restrict__ inp, const float* __restrict__ shift,
    const float* __restrict__ lscale, unsigned short* __restrict__ sgT)
{
  __shared__ float T[64][257];
  const int b0 = blockIdx.x * 64;
  const int t = threadIdx.x;
  {
    const int r = t & 63, q = t >> 6;
    const float* src = inp + (size_t)(b0 + r) * F + q * 64;
    #pragma unroll
    for (int i = 0; i < 16; ++i) {
      float4 v = *(const float4*)(src + i * 4);
      T[r][q * 64 + i * 4 + 0] = v.x;
      T[r][q * 64 + i * 4 + 1] = v.y;
      T[r][q * 64 + i * 4 + 2] = v.z;
      T[r][q * 64 + i * 4 + 3] = v.w;
    }
  }
  __syncthreads();
  const int f = t;
  float ls = lscale[f];
  const float sc = fmaxf(ls, 0.0f) + __logf(1.0f + __expf(-fabsf(ls))) + 0.001f;
  const float sh = shift[f];
  unsigned short* dst = sgT + (size_t)f * BATCH + b0;
  #pragma unroll
  for (int r8 = 0; r8 < 8; ++r8) {
    unsigned short h[8];
    #pragma unroll
    for (int j = 0; j < 8; ++j) {
      const float z = (T[r8 * 8 + j][f] - sh) * sc;
      const float sg = 1.0f / (1.0f + __expf(-z));
      h[j] = (unsigned short)fminf(sg * 65536.0f, 65535.0f);
    }
    *(s16x8*)(dst + r8 * 8) = *(s16x8*)h;
  }
}

// ---------------- pre-pass: B (coeffs + skip_w) -> bf16 fragment-major ----------------
// frag id = (((c*4 + nt)*2 + wnB)*4 + nfB)*2 + kk, within frag: lane*8 shorts
//   w = nt*128 + wnB*64 + nfB*16 + (lane&15);  k = c*64 + kk*32 + (lane>>4)*8 + j
__global__ __launch_bounds__(256) void bws_build(
    const float* __restrict__ coeffs, const float* __restrict__ skip_w,
    short* __restrict__ Bws)
{
  const int gid = blockIdx.x * 256 + threadIdx.x;   // 0 .. 540671
  const int lane = gid & 63;
  const int kk = (gid >> 6) & 1;
  const int nf = (gid >> 7) & 3;
  const int wn = (gid >> 9) & 1;
  const int nt = (gid >> 10) & 3;
  const int c  = gid >> 12;
  const int w  = nt * 128 + wn * 64 + nf * 16 + (lane & 15);
  const int kl = kk * 32 + (lane >> 4) * 8;
  const float* src = (c < 128) ? (coeffs + (size_t)(c * 64 + kl) * W + w)
                               : (skip_w + (size_t)((c - 128) * 64 + kl) * W + w);
  s16x8 h;
  #pragma unroll
  for (int j = 0; j < 8; ++j) h[j] = f2bf(src[(size_t)j * W]);
  ((s16x8*)Bws)[gid] = h;
}

// ---------------- A staging for 64-row tiles: spline (funnel window) or input copy ----------------
__device__ __forceinline__ void stage_a64(short* __restrict__ dst, int cc,
    int tid, int m0, const unsigned short* __restrict__ sgT,
    const float* __restrict__ inp)
{
  if (cc < 128) {
    if (tid < 128) {
      const int bp = tid & 63;
      const int hi = tid >> 6;           // feature index within chunk -> also kk
      const int mf = bp >> 4, l15b = bp & 15;
      short* base = dst + ((mf * 2 + hi) * 64 + l15b) * 8;
      const float sg = ((float)sgT[(size_t)(2 * cc + hi) * BATCH + m0 + bp] + 0.5f) * (1.0f / 65536.0f);
      const int s0 = (int)(sg * 29.0f);  // in [0,28]
      const int sp = s0 + 3;
      float Nv[4], lef[4], rig[4];
      Nv[0] = 1.0f;
      #pragma unroll
      for (int r = 1; r <= 3; ++r) {
        lef[r] = sg - knotv(sp + 1 - r);
        rig[r] = knotv(sp + r) - sg;
        float saved = 0.0f;
        #pragma unroll
        for (int j = 0; j < r; ++j) {
          float temp = fdiv_fast(Nv[j], rig[j + 1] + lef[r - j]);
          Nv[j] = saved + rig[j + 1] * temp;
          saved = lef[r - j] * temp;
        }
        Nv[r] = saved;
      }
      unsigned long long nv =
          (unsigned long long)(unsigned short)f2bf(Nv[0])
        | ((unsigned long long)(unsigned short)f2bf(Nv[1]) << 16)
        | ((unsigned long long)(unsigned short)f2bf(Nv[2]) << 32)
        | ((unsigned long long)(unsigned short)f2bf(Nv[3]) << 48);
      const int p = s0 & 7, ga = s0 >> 3;
      const int s = 16 * p, shl = s & 63;
      const unsigned long long a = nv << shl;
      const unsigned long long b = (nv >> (63 - shl)) >> 1;
      const bool hs = (s >= 64);
      i64x2 d0, d1, z;
      d0[0] = hs ? 0ll : (long long)a;
      d0[1] = hs ? (long long)a : (long long)b;
      d1[0] = hs ? (long long)b : 0ll;
      d1[1] = 0ll;
      z[0] = 0ll; z[1] = 0ll;
      *(i64x2*)(base + ga * 128) = d0;
      *(i64x2*)(base + ((ga + 1) & 3) * 128) = d1;
      *(i64x2*)(base + ((ga + 2) & 3) * 128) = z;
      *(i64x2*)(base + ((ga + 3) & 3) * 128) = z;
    }
  } else {
    const int bp = tid & 63;
    const int hi = (tid >> 6) & 1;       // k-half (kk)
    const int lqh = tid >> 7;            // 0..1 -> lane-quads {0,1} or {2,3}
    const int mf = bp >> 4, l15b = bp & 15;
    short* base = dst + ((mf * 2 + hi) * 64 + l15b) * 8;
    const int sb = (cc - 128) * 64 + hi * 32;
    const float* ip = inp + (size_t)(m0 + bp) * F + sb;
    #pragma unroll
    for (int t = 0; t < 2; ++t) {
      const int lq = lqh * 2 + t;
      s16x8 h;
      #pragma unroll
      for (int j = 0; j < 8; ++j) h[j] = f2bf(ip[lq * 8 + j]);
      *(s16x8*)(base + lq * 128) = h;
    }
  }
}

__device__ __forceinline__ void load_b(int c, int nt, int wn, int lane,
                                       const short* __restrict__ Bws, s16x8 (&b)[4]) {
  const int wnB = wn >> 1, lo = wn & 1;
  #pragma unroll
  for (int nf = 0; nf < 2; ++nf)
    #pragma unroll
    for (int kk = 0; kk < 2; ++kk) {
      const size_t frag = ((((size_t)c * 4 + nt) * 2 + wnB) * 4 + (lo * 2 + nf)) * 2 + kk;
      b[nf * 2 + kk] = *((const s16x8*)(Bws + frag * 512) + lane);
    }
}

// ---------------- main GEMM: 64x128 tiles, 4 waves of 64x32, 2 blocks/CU ----------------
__global__ __launch_bounds__(256, 2) void kan_gemm_v5(
    const float* __restrict__ inp, const unsigned short* __restrict__ sgT,
    const short* __restrict__ Bws,
    const float* __restrict__ bias, const float* __restrict__ skip_b,
    float* __restrict__ out)
{
  __shared__ short Abuf0[4096];   // 8KB: 64 rows x 64 k, fragment-major
  __shared__ short Abuf1[4096];

  const int tid = threadIdx.x;
  const int lane = tid & 63;
  const int wn = tid >> 6;        // 4 waves: 1m x 4n, wave tile 64x32

  // XCD-bijective swizzle: 512 blocks = 8 XCDs x 64
  const int nb = (blockIdx.x & 7) * 64 + (blockIdx.x >> 3);
  const int mt = nb >> 2, nt = nb & 3;
  const int m0 = mt * 64, n0 = nt * 128;

  f32x4 acc[4][2];
  #pragma unroll
  for (int i = 0; i < 4; ++i)
    #pragma unroll
    for (int j = 0; j < 2; ++j)
      acc[i][j] = (f32x4){0.f, 0.f, 0.f, 0.f};

  s16x8 b0[4], b1[4];
  load_b(0, nt, wn, lane, Bws, b0);
  stage_a64(Abuf0, 0, tid, m0, sgT, inp);

#define CHUNK(ACUR, ANXT, BCUR, BNXT, C_) do {                                  \
    const int c_ = (C_);                                                        \
    asm volatile("s_waitcnt lgkmcnt(0)" ::: "memory");                          \
    __builtin_amdgcn_s_barrier();                                               \
    if (c_ + 1 < NCHUNK) {                                                      \
      load_b(c_ + 1, nt, wn, lane, Bws, BNXT);                                  \
      stage_a64(ANXT, c_ + 1, tid, m0, sgT, inp);                               \
    }                                                                           \
    __builtin_amdgcn_s_setprio(1);                                              \
    _Pragma("unroll")                                                           \
    for (int kk = 0; kk < 2; ++kk)                                              \
      _Pragma("unroll")                                                         \
      for (int mf = 0; mf < 4; ++mf) {                                          \
        s16x8 af = *(const s16x8*)&ACUR[((mf * 2 + kk) * 64 + lane) * 8];       \
        _Pragma("unroll")                                                       \
        for (int nf = 0; nf < 2; ++nf)                                          \
          acc[mf][nf] = __builtin_amdgcn_mfma_f32_16x16x32_bf16(                \
              af, BCUR[nf * 2 + kk], acc[mf][nf], 0, 0, 0);                     \
      }                                                                         \
    __builtin_amdgcn_s_setprio(0);                                              \
  } while (0)

  for (int c = 0; c < NCHUNK; c += 2) {
    CHUNK(Abuf0, Abuf1, b0, b1, c);
    CHUNK(Abuf1, Abuf0, b1, b0, c + 1);
  }
#undef CHUNK

  // ---------- epilogue ----------
  const int l15 = lane & 15;
  const int lq = lane >> 4;
  #pragma unroll
  for (int nf = 0; nf < 2; ++nf) {
    const int col = n0 + wn * 32 + nf * 16 + l15;
    const float badd = bias[col] + skip_b[col];
    #pragma unroll
    for (int mf = 0; mf < 4; ++mf) {
      const int r0 = m0 + mf * 16 + lq * 4;
      #pragma unroll
      for (int r = 0; r < 4; ++r)
        out[(size_t)(r0 + r) * W + col] = acc[mf][nf][r] + badd;
    }
  }
}

// ---------------- fallback GEMM (no ws) — round-2 kernel ----------------
__device__ __forceinline__ void issue_b(int c, int uu, int n0,
                                        const float* __restrict__ coeffs,
                                        const float* __restrict__ skip_w,
                                        float (&r)[4][8]) {
  const float* base = (c < 128) ? (coeffs + (size_t)c * 64 * W)
                                : (skip_w + (size_t)(c - 128) * 64 * W);
  const int kk = (uu >> 6) & 1;
  const int lq = (uu >> 4) & 3;
  const int l15 = uu & 15;
  const int u7 = uu >> 7;
  #pragma unroll
  for (int s = 0; s < 4; ++s) {
    const int w = (2 * s + u7) * 16 + l15;
    const float* p = base + (size_t)(kk * 32 + lq * 8) * W + n0 + w;
    #pragma unroll
    for (int j = 0; j < 8; ++j) r[s][j] = p[(size_t)j * W];
  }
}

__global__ __launch_bounds__(512, 1) void kan_gemm_v2(
    const float* __restrict__ inp, const float* __restrict__ shift,
    const float* __restrict__ lscale, const float* __restrict__ coeffs,
    const float* __restrict__ bias, const float* __restrict__ skip_w,
    const float* __restrict__ skip_b, float* __restrict__ out)
{
  __shared__ short Abuf[2][8192];
  __shared__ short Bbuf[2][8192];
  __shared__ unsigned short sgl[F * 128];

  const int tid = threadIdx.x;
  const int lane = tid & 63;
  const int wid = tid >> 6;
  const int nb = (blockIdx.x & 7) * 32 + (blockIdx.x >> 3);
  const int mt = nb >> 2;
  const int nt = nb & 3;
  const int m0 = mt * 128;
  const int n0 = nt * 128;

  float bpref[4][8];
  if (tid >= 256) issue_b(0, tid - 256, n0, coeffs, skip_w, bpref);

  float* shf = (float*)&Abuf[0][0];
  if (tid < 256) {
    float ls = lscale[tid];
    shf[tid] = fmaxf(ls, 0.0f) + __logf(1.0f + __expf(-fabsf(ls))) + 0.001f;
    shf[256 + tid] = shift[tid];
  }
  __syncthreads();

  {
    const int row = tid & 127;
    const int q = tid >> 7;
    const float* ip = inp + (size_t)(m0 + row) * F + q * 64;
    #pragma unroll
    for (int i = 0; i < 16; ++i) {
      float4 v = *(const float4*)(ip + i * 4);
      float vv[4] = {v.x, v.y, v.z, v.w};
      #pragma unroll
      for (int j = 0; j < 4; ++j) {
        const int f = q * 64 + i * 4 + j;
        const float z = (vv[j] - shf[256 + f]) * shf[f];
        const float sg = 1.0f / (1.0f + __expf(-z));
        sgl[f * 128 + row] = (unsigned short)fminf(sg * 65536.0f, 65535.0f);
      }
    }
  }
  __syncthreads();

  const int wm = wid >> 2;
  const int wn = wid & 3;

  f32x4 acc[4][2];
  #pragma unroll
  for (int i = 0; i < 4; ++i)
    #pragma unroll
    for (int j = 0; j < 2; ++j)
      acc[i][j] = (f32x4){0.f, 0.f, 0.f, 0.f};

  for (int c = 0; c < NCHUNK; ++c) {
    short* Ab = Abuf[c & 1];
    short* Bb = Bbuf[c & 1];

    if (c < 128) {
      s16x8 z = {0, 0, 0, 0, 0, 0, 0, 0};
      ((s16x8*)Ab)[tid * 2] = z;
      ((s16x8*)Ab)[tid * 2 + 1] = z;
    } else if (tid < 256) {
      const int bp = tid & 127, fi = tid >> 7;
      const int sb = (c - 128) * 64 + fi * 32;
      const float* ip = inp + (size_t)(m0 + bp) * F + sb;
      const int rg = bp >> 4, l15b = bp & 15;
      #pragma unroll
      for (int lq2 = 0; lq2 < 4; ++lq2) {
        s16x8 h;
        #pragma unroll
        for (int j = 0; j < 8; ++j) h[j] = f2bf(ip[lq2 * 8 + j]);
        *(s16x8*)&Ab[((rg * 2 + fi) * 64 + lq2 * 16 + l15b) * 8] = h;
      }
    }
    if (tid >= 256) {
      const int uu = tid - 256;
      #pragma unroll
      for (int s = 0; s < 4; ++s) {
        s16x8 h;
        #pragma unroll
        for (int j = 0; j < 8; ++j) h[j] = f2bf(bpref[s][j]);
        *(s16x8*)&Bb[(s * 256 + uu) * 8] = h;
      }
      if (c + 1 < NCHUNK) issue_b(c + 1, uu, n0, coeffs, skip_w, bpref);
    }
    __syncthreads();

    if (c < 128 && tid < 256) {
      const int bp = tid & 127, fi = tid >> 7;
      const int f = 2 * c + fi;
      const float sg = ((float)sgl[f * 128 + bp] + 0.5f) * (1.0f / 65536.0f);
      int s0 = (int)floorf(sg * 29.0f);
      s0 = s0 < 0 ? 0 : (s0 > 28 ? 28 : s0);
      const int sp = s0 + 3;
      float Nv[4], lef[4], rig[4];
      Nv[0] = 1.0f;
      #pragma unroll
      for (int r = 1; r <= 3; ++r) {
        lef[r] = sg - knotv(sp + 1 - r);
        rig[r] = knotv(sp + r) - sg;
        float saved = 0.0f;
        #pragma unroll
        for (int j = 0; j < r; ++j) {
          float temp = fdiv_fast(Nv[j], rig[j + 1] + lef[r - j]);
          Nv[j] = saved + rig[j + 1] * temp;
          saved = lef[r - j] * temp;
        }
        Nv[r] = saved;
      }
      const int rg = bp >> 4, l15b = bp & 15;
      #pragma unroll
      for (int t = 0; t < 4; ++t) {
        const int g = s0 + t;
        Ab[((rg * 2 + fi) * 64 + (g >> 3) * 16 + l15b) * 8 + (g & 7)] = f2bf(Nv[t]);
      }
    }
    s16x8 bfv[2][2];
    #pragma unroll
    for (int nf = 0; nf < 2; ++nf)
      #pragma unroll
      for (int kk = 0; kk < 2; ++kk)
        bfv[nf][kk] = *(const s16x8*)&Bb[(((wn * 2 + nf) * 2 + kk) * 64 + lane) * 8];
    __syncthreads();

    #pragma unroll
    for (int kk = 0; kk < 2; ++kk) {
      #pragma unroll
      for (int mf = 0; mf < 4; ++mf) {
        s16x8 af = *(const s16x8*)&Ab[(((wm * 4 + mf) * 2 + kk) * 64 + lane) * 8];
        #pragma unroll
        for (int nf = 0; nf < 2; ++nf)
          acc[mf][nf] = __builtin_amdgcn_mfma_f32_16x16x32_bf16(af, bfv[nf][kk], acc[mf][nf], 0, 0, 0);
      }
    }
  }

  const int l15 = lane & 15;
  const int lq = lane >> 4;
  #pragma unroll
  for (int nf = 0; nf < 2; ++nf) {
    const int col = n0 + wn * 32 + nf * 16 + l15;
    const float badd = bias[col] + skip_b[col];
    #pragma unroll
    for (int mf = 0; mf < 4; ++mf) {
      const int r0 = m0 + wm * 64 + mf * 16 + lq * 4;
      #pragma unroll
      for (int r = 0; r < 4; ++r)
        out[(size_t)(r0 + r) * W + col] = acc[mf][nf][r] + badd;
    }
  }
}

__global__ __launch_bounds__(256, 1) void ln_gelu(
    float* __restrict__ out, const float* __restrict__ gamma,
    const float* __restrict__ beta)
{
  const int lane = threadIdx.x & 63;
  const int wid = threadIdx.x >> 6;
  const int row = blockIdx.x * 4 + wid;
  float* p = out + (size_t)row * W + lane * 8;
  float4 a = *(const float4*)p;
  float4 b = *(const float4*)(p + 4);
  float v[8] = {a.x, a.y, a.z, a.w, b.x, b.y, b.z, b.w};
  float s = 0.f, q = 0.f;
  #pragma unroll
  for (int j = 0; j < 8; ++j) { s += v[j]; q += v[j] * v[j]; }
  #pragma unroll
  for (int m = 1; m < 64; m <<= 1) {
    s += __shfl_xor(s, m);
    q += __shfl_xor(q, m);
  }
  const float mu = s * (1.0f / 512.0f);
  const float var = q * (1.0f / 512.0f) - mu * mu;
  const float inv = rsqrtf(var + 1e-5f);
  const float4 g0 = *(const float4*)(gamma + lane * 8);
  const float4 g1 = *(const float4*)(gamma + lane * 8 + 4);
  const float4 b0 = *(const float4*)(beta + lane * 8);
  const float4 b1 = *(const float4*)(beta + lane * 8 + 4);
  float gm[8] = {g0.x, g0.y, g0.z, g0.w, g1.x, g1.y, g1.z, g1.w};
  float bt[8] = {b0.x, b0.y, b0.z, b0.w, b1.x, b1.y, b1.z, b1.w};
  float o[8];
  #pragma unroll
  for (int j = 0; j < 8; ++j) {
    float x = (v[j] - mu) * inv * gm[j] + bt[j];
    o[j] = 0.5f * x * (1.0f + erff(x * 0.70710678f));
  }
  float4 w0 = {o[0], o[1], o[2], o[3]};
  float4 w1 = {o[4], o[5], o[6], o[7]};
  *(float4*)p = w0;
  *(float4*)(p + 4) = w1;
}

extern "C" void kernel_launch(void* const* d_in, const int* in_sizes, int n_in,
                              void* d_out, int out_size, void* d_ws, size_t ws_size,
                              hipStream_t stream) {
  (void)in_sizes; (void)n_in; (void)out_size;
  const float* inp    = (const float*)d_in[0];
  const float* shift  = (const float*)d_in[1];
  const float* lscale = (const float*)d_in[2];
  const float* coeffs = (const float*)d_in[3];
  const float* bias   = (const float*)d_in[4];
  const float* skip_w = (const float*)d_in[5];
  const float* skip_b = (const float*)d_in[6];
  const float* gamma  = (const float*)d_in[7];
  const float* beta   = (const float*)d_in[8];
  float* out = (float*)d_out;

  const size_t needB = (size_t)NCHUNK * 4 * 16384;   // 8,650,752
  const size_t needS = (size_t)F * BATCH * 2;        // 4,194,304

  if (ws_size >= needB + needS) {
    short* Bws = (short*)d_ws;
    unsigned short* sgT = (unsigned short*)((char*)d_ws + needB);
    sig_build<<<dim3(BATCH / 64), dim3(256), 0, stream>>>(inp, shift, lscale, sgT);
    bws_build<<<dim3(2112), dim3(256), 0, stream>>>(coeffs, skip_w, Bws);
    kan_gemm_v5<<<dim3(512), dim3(256), 0, stream>>>(
        inp, sgT, Bws, bias, skip_b, out);
  } else {
    kan_gemm_v2<<<dim3(256), dim3(512), 0, stream>>>(
        inp, shift, lscale, coeffs, bias, skip_w, skip_b, out);
  }
  ln_gelu<<<dim3(BATCH / 4), dim3(256), 0, stream>>>(out, gamma, beta);
}

// Round 6
// 107.687 us; speedup vs baseline: 1.6624x; 1.4325x over previous
//
#include <hip/hip_runtime.h>
#include <hip/hip_bf16.h>
#include <math.h>

#define BATCH 8192
#define F 256
#define G 32
#define W 512
#define NCHUNK 132   // 128 spline chunks (2 features x 32 g) + 4 skip chunks (64 k each)
#define NPER 66      // periods of 2 chunks

typedef float f32x4 __attribute__((ext_vector_type(4)));
typedef short s16x8 __attribute__((ext_vector_type(8)));
typedef long long i64x2 __attribute__((ext_vector_type(2)));

__device__ __forceinline__ short f2bf(float f) {
  unsigned int u = __builtin_bit_cast(unsigned int, f);
  u += 0x7fffu + ((u >> 16) & 1u);
  return (short)(u >> 16);
}

__device__ __forceinline__ float knotv(int i) {
  int j = i - 3;
  j = j < 0 ? 0 : (j > 29 ? 29 : j);
  return (float)j * (1.0f / 29.0f);
}

__device__ __forceinline__ float fdiv_fast(float a, float b) {
  return a * __builtin_amdgcn_rcpf(b);
}

// ---------------- pre-pass: B (coeffs + skip_w) -> bf16 fragment-major ----------------
// frag = c*64 + nt*16 + wnB*8 + nfq*2 + kk; within frag lane*8 shorts
//   w = nt*128 + wnB*64 + nfq*16 + (lane&15);  k = c*64 + kk*32 + (lane>>4)*8 + j
__global__ __launch_bounds__(256) void bws_build(
    const float* __restrict__ coeffs, const float* __restrict__ skip_w,
    short* __restrict__ Bws)
{
  const int gid = blockIdx.x * 256 + threadIdx.x;   // 0 .. 540671
  const int lane = gid & 63;
  const int kk = (gid >> 6) & 1;
  const int nf = (gid >> 7) & 3;
  const int wn = (gid >> 9) & 1;
  const int nt = (gid >> 10) & 3;
  const int c  = gid >> 12;
  const int w  = nt * 128 + wn * 64 + nf * 16 + (lane & 15);
  const int kl = kk * 32 + (lane >> 4) * 8;
  const float* src = (c < 128) ? (coeffs + (size_t)(c * 64 + kl) * W + w)
                               : (skip_w + (size_t)((c - 128) * 64 + kl) * W + w);
  s16x8 h;
  #pragma unroll
  for (int j = 0; j < 8; ++j) h[j] = f2bf(src[(size_t)j * W]);
  ((s16x8*)Bws)[gid] = h;
}

// ---------------- A staging: one item per thread per 2-chunk period ----------------
__device__ __forceinline__ void stage_period(short* __restrict__ Ab, int p,
    int tid, int m0, const unsigned short* __restrict__ sgl,
    const float* __restrict__ inp)
{
  const int ci = tid >> 7;             // which chunk of the period
  const int hi = (tid >> 6) & 1;       // feature-within-chunk == kk half
  const int bp = tid & 63;             // row
  const int cc = 2 * p + ci;
  const int mf = bp >> 4, l15b = bp & 15;
  short* base = Ab + ci * 4096 + ((mf * 2 + hi) * 64 + l15b) * 8;
  if (cc < 128) {
    const float sg = ((float)sgl[(2 * cc + hi) * 64 + bp] + 0.5f) * (1.0f / 65536.0f);
    const int s0 = (int)(sg * 29.0f);  // in [0,28]
    const int sp = s0 + 3;
    float Nv[4], lef[4], rig[4];
    Nv[0] = 1.0f;
    #pragma unroll
    for (int r = 1; r <= 3; ++r) {
      lef[r] = sg - knotv(sp + 1 - r);
      rig[r] = knotv(sp + r) - sg;
      float saved = 0.0f;
      #pragma unroll
      for (int j = 0; j < r; ++j) {
        float temp = fdiv_fast(Nv[j], rig[j + 1] + lef[r - j]);
        Nv[j] = saved + rig[j + 1] * temp;
        saved = lef[r - j] * temp;
      }
      Nv[r] = saved;
    }
    unsigned long long nv =
        (unsigned long long)(unsigned short)f2bf(Nv[0])
      | ((unsigned long long)(unsigned short)f2bf(Nv[1]) << 16)
      | ((unsigned long long)(unsigned short)f2bf(Nv[2]) << 32)
      | ((unsigned long long)(unsigned short)f2bf(Nv[3]) << 48);
    const int pp = s0 & 7, ga = s0 >> 3;
    const int s = 16 * pp, shl = s & 63;
    const unsigned long long a = nv << shl;
    const unsigned long long b = (nv >> (63 - shl)) >> 1;
    const bool hs = (s >= 64);
    i64x2 d0, d1, z;
    d0[0] = hs ? 0ll : (long long)a;
    d0[1] = hs ? (long long)a : (long long)b;
    d1[0] = hs ? (long long)b : 0ll;
    d1[1] = 0ll;
    z[0] = 0ll; z[1] = 0ll;
    *(i64x2*)(base + ga * 128) = d0;
    *(i64x2*)(base + ((ga + 1) & 3) * 128) = d1;
    *(i64x2*)(base + ((ga + 2) & 3) * 128) = z;
    *(i64x2*)(base + ((ga + 3) & 3) * 128) = z;
  } else {
    const int sb = (cc - 128) * 64 + hi * 32;
    const float* ip = inp + (size_t)(m0 + bp) * F + sb;
    #pragma unroll
    for (int lq = 0; lq < 4; ++lq) {
      s16x8 h;
      #pragma unroll
      for (int j = 0; j < 8; ++j) h[j] = f2bf(ip[lq * 8 + j]);
      *(s16x8*)(base + lq * 128) = h;
    }
  }
}

// ---------------- main GEMM: 64x128 tiles, 2-chunk periods, B global->reg ----------------
__global__ __launch_bounds__(256, 2) void kan_gemm_v6(
    const float* __restrict__ inp, const float* __restrict__ shift,
    const float* __restrict__ lscale, const short* __restrict__ Bws,
    const float* __restrict__ bias, const float* __restrict__ skip_b,
    float* __restrict__ out)
{
  __shared__ short Abuf[2][8192];          // [buf][ci*4096 + frag-major]
  __shared__ unsigned short sgl[F * 64];   // 32KB: sg[f][row]
  __shared__ float shf[2 * F];

  const int tid = threadIdx.x;
  const int lane = tid & 63;
  const int wn = tid >> 6;                 // wave id: 1m x 4n

  // XCD-bijective swizzle: 512 blocks = 8 XCDs x 64
  const int nb = (blockIdx.x & 7) * 64 + (blockIdx.x >> 3);
  const int mt = nb >> 2, nt = nb & 3;
  const int m0 = mt * 64, n0 = nt * 128;

  // ---- softplus scale / shift ----
  {
    float ls = lscale[tid];
    shf[tid] = fmaxf(ls, 0.0f) + __logf(1.0f + __expf(-fabsf(ls))) + 0.001f;
    shf[256 + tid] = shift[tid];
  }
  __syncthreads();

  // ---- sigmoid prologue: sgl[f][row], u16 ----
  {
    const int row = lane;                  // 0..63
    const int qc = wn;                     // 64 cols per wave
    const float* ip = inp + (size_t)(m0 + row) * F + qc * 64;
    #pragma unroll
    for (int i = 0; i < 16; ++i) {
      float4 v = *(const float4*)(ip + i * 4);
      float vv[4] = {v.x, v.y, v.z, v.w};
      #pragma unroll
      for (int j = 0; j < 4; ++j) {
        const int f = qc * 64 + i * 4 + j;
        const float z = (vv[j] - shf[256 + f]) * shf[f];
        const float sg = 1.0f / (1.0f + __expf(-z));
        sgl[f * 64 + row] = (unsigned short)fminf(sg * 65536.0f, 65535.0f);
      }
    }
  }
  __syncthreads();

  f32x4 acc[4][2];
  #pragma unroll
  for (int i = 0; i < 4; ++i)
    #pragma unroll
    for (int j = 0; j < 2; ++j)
      acc[i][j] = (f32x4){0.f, 0.f, 0.f, 0.f};

  // per-thread B pointers (fragment-major; const offsets within a period)
  const int wnB = wn >> 1, lo = wn & 1;
  const short* bq0 = Bws + (size_t)(nt * 16 + wnB * 8 + lo * 4) * 512 + lane * 8;
  const short* bq1 = bq0 + 32768;          // second chunk of period

#define LOADB(BS) do {                                                          \
    _Pragma("unroll")                                                           \
    for (int nf = 0; nf < 2; ++nf)                                              \
      _Pragma("unroll")                                                         \
      for (int kk = 0; kk < 2; ++kk) {                                          \
        BS[0 * 4 + nf * 2 + kk] = *(const s16x8*)(bq0 + nf * 1024 + kk * 512);  \
        BS[1 * 4 + nf * 2 + kk] = *(const s16x8*)(bq1 + nf * 1024 + kk * 512);  \
      }                                                                         \
    bq0 += 65536; bq1 += 65536;                                                 \
  } while (0)

#define MMAC(AB, BS)                                                            \
    _Pragma("unroll")                                                           \
    for (int ci = 0; ci < 2; ++ci)                                              \
      _Pragma("unroll")                                                         \
      for (int kk = 0; kk < 2; ++kk)                                            \
        _Pragma("unroll")                                                       \
        for (int mf = 0; mf < 4; ++mf) {                                        \
          s16x8 af = *(const s16x8*)&AB[ci * 4096 + ((mf * 2 + kk) * 64 + lane) * 8]; \
          _Pragma("unroll")                                                     \
          for (int nf = 0; nf < 2; ++nf)                                        \
            acc[mf][nf] = __builtin_amdgcn_mfma_f32_16x16x32_bf16(              \
                af, BS[ci * 4 + nf * 2 + kk], acc[mf][nf], 0, 0, 0);            \
        }

#define PERIOD(P_, ACUR, ANXT, BCUR, BNXT) do {                                 \
    asm volatile("s_waitcnt lgkmcnt(0)" ::: "memory");                          \
    __builtin_amdgcn_s_barrier();                                               \
    if ((P_) + 1 < NPER) LOADB(BNXT);                                           \
    __builtin_amdgcn_s_setprio(1);                                              \
    MMAC(ACUR, BCUR);                                                           \
    __builtin_amdgcn_s_setprio(0);                                              \
    if ((P_) + 1 < NPER) stage_period(ANXT, (P_) + 1, tid, m0, sgl, inp);       \
  } while (0)

  s16x8 bA[8], bB[8];
  LOADB(bA);
  stage_period(&Abuf[0][0], 0, tid, m0, sgl, inp);

  for (int p = 0; p < NPER; p += 2) {
    PERIOD(p,     Abuf[0], (&Abuf[1][0]), bA, bB);
    PERIOD(p + 1, Abuf[1], (&Abuf[0][0]), bB, bA);
  }
#undef PERIOD
#undef MMAC
#undef LOADB

  // ---------- epilogue ----------
  const int l15 = lane & 15;
  const int lq = lane >> 4;
  #pragma unroll
  for (int nf = 0; nf < 2; ++nf) {
    const int col = n0 + wn * 32 + nf * 16 + l15;
    const float badd = bias[col] + skip_b[col];
    #pragma unroll
    for (int mf = 0; mf < 4; ++mf) {
      const int r0 = m0 + mf * 16 + lq * 4;
      #pragma unroll
      for (int r = 0; r < 4; ++r)
        out[(size_t)(r0 + r) * W + col] = acc[mf][nf][r] + badd;
    }
  }
}

// ---------------- fallback GEMM (no ws) — round-2 kernel ----------------
__device__ __forceinline__ void issue_b(int c, int uu, int n0,
                                        const float* __restrict__ coeffs,
                                        const float* __restrict__ skip_w,
                                        float (&r)[4][8]) {
  const float* base = (c < 128) ? (coeffs + (size_t)c * 64 * W)
                                : (skip_w + (size_t)(c - 128) * 64 * W);
  const int kk = (uu >> 6) & 1;
  const int lq = (uu >> 4) & 3;
  const int l15 = uu & 15;
  const int u7 = uu >> 7;
  #pragma unroll
  for (int s = 0; s < 4; ++s) {
    const int w = (2 * s + u7) * 16 + l15;
    const float* p = base + (size_t)(kk * 32 + lq * 8) * W + n0 + w;
    #pragma unroll
    for (int j = 0; j < 8; ++j) r[s][j] = p[(size_t)j * W];
  }
}

__global__ __launch_bounds__(512, 1) void kan_gemm_v2(
    const float* __restrict__ inp, const float* __restrict__ shift,
    const float* __restrict__ lscale, const float* __restrict__ coeffs,
    const float* __restrict__ bias, const float* __restrict__ skip_w,
    const float* __restrict__ skip_b, float* __restrict__ out)
{
  __shared__ short Abuf[2][8192];
  __shared__ short Bbuf[2][8192];
  __shared__ unsigned short sgl[F * 128];

  const int tid = threadIdx.x;
  const int lane = tid & 63;
  const int wid = tid >> 6;
  const int nb = (blockIdx.x & 7) * 32 + (blockIdx.x >> 3);
  const int mt = nb >> 2;
  const int nt = nb & 3;
  const int m0 = mt * 128;
  const int n0 = nt * 128;

  float bpref[4][8];
  if (tid >= 256) issue_b(0, tid - 256, n0, coeffs, skip_w, bpref);

  float* shf = (float*)&Abuf[0][0];
  if (tid < 256) {
    float ls = lscale[tid];
    shf[tid] = fmaxf(ls, 0.0f) + __logf(1.0f + __expf(-fabsf(ls))) + 0.001f;
    shf[256 + tid] = shift[tid];
  }
  __syncthreads();

  {
    const int row = tid & 127;
    const int q = tid >> 7;
    const float* ip = inp + (size_t)(m0 + row) * F + q * 64;
    #pragma unroll
    for (int i = 0; i < 16; ++i) {
      float4 v = *(const float4*)(ip + i * 4);
      float vv[4] = {v.x, v.y, v.z, v.w};
      #pragma unroll
      for (int j = 0; j < 4; ++j) {
        const int f = q * 64 + i * 4 + j;
        const float z = (vv[j] - shf[256 + f]) * shf[f];
        const float sg = 1.0f / (1.0f + __expf(-z));
        sgl[f * 128 + row] = (unsigned short)fminf(sg * 65536.0f, 65535.0f);
      }
    }
  }
  __syncthreads();

  const int wm = wid >> 2;
  const int wn = wid & 3;

  f32x4 acc[4][2];
  #pragma unroll
  for (int i = 0; i < 4; ++i)
    #pragma unroll
    for (int j = 0; j < 2; ++j)
      acc[i][j] = (f32x4){0.f, 0.f, 0.f, 0.f};

  for (int c = 0; c < NCHUNK; ++c) {
    short* Ab = Abuf[c & 1];
    short* Bb = Bbuf[c & 1];

    if (c < 128) {
      s16x8 z = {0, 0, 0, 0, 0, 0, 0, 0};
      ((s16x8*)Ab)[tid * 2] = z;
      ((s16x8*)Ab)[tid * 2 + 1] = z;
    } else if (tid < 256) {
      const int bp = tid & 127, fi = tid >> 7;
      const int sb = (c - 128) * 64 + fi * 32;
      const float* ip = inp + (size_t)(m0 + bp) * F + sb;
      const int rg = bp >> 4, l15b = bp & 15;
      #pragma unroll
      for (int lq2 = 0; lq2 < 4; ++lq2) {
        s16x8 h;
        #pragma unroll
        for (int j = 0; j < 8; ++j) h[j] = f2bf(ip[lq2 * 8 + j]);
        *(s16x8*)&Ab[((rg * 2 + fi) * 64 + lq2 * 16 + l15b) * 8] = h;
      }
    }
    if (tid >= 256) {
      const int uu = tid - 256;
      #pragma unroll
      for (int s = 0; s < 4; ++s) {
        s16x8 h;
        #pragma unroll
        for (int j = 0; j < 8; ++j) h[j] = f2bf(bpref[s][j]);
        *(s16x8*)&Bb[(s * 256 + uu) * 8] = h;
      }
      if (c + 1 < NCHUNK) issue_b(c + 1, uu, n0, coeffs, skip_w, bpref);
    }
    __syncthreads();

    if (c < 128 && tid < 256) {
      const int bp = tid & 127, fi = tid >> 7;
      const int f = 2 * c + fi;
      const float sg = ((float)sgl[f * 128 + bp] + 0.5f) * (1.0f / 65536.0f);
      int s0 = (int)floorf(sg * 29.0f);
      s0 = s0 < 0 ? 0 : (s0 > 28 ? 28 : s0);
      const int sp = s0 + 3;
      float Nv[4], lef[4], rig[4];
      Nv[0] = 1.0f;
      #pragma unroll
      for (int r = 1; r <= 3; ++r) {
        lef[r] = sg - knotv(sp + 1 - r);
        rig[r] = knotv(sp + r) - sg;
        float saved = 0.0f;
        #pragma unroll
        for (int j = 0; j < r; ++j) {
          float temp = fdiv_fast(Nv[j], rig[j + 1] + lef[r - j]);
          Nv[j] = saved + rig[j + 1] * temp;
          saved = lef[r - j] * temp;
        }
        Nv[r] = saved;
      }
      const int rg = bp >> 4, l15b = bp & 15;
      #pragma unroll
      for (int t = 0; t < 4; ++t) {
        const int g = s0 + t;
        Ab[((rg * 2 + fi) * 64 + (g >> 3) * 16 + l15b) * 8 + (g & 7)] = f2bf(Nv[t]);
      }
    }
    s16x8 bfv[2][2];
    #pragma unroll
    for (int nf = 0; nf < 2; ++nf)
      #pragma unroll
      for (int kk = 0; kk < 2; ++kk)
        bfv[nf][kk] = *(const s16x8*)&Bb[(((wn * 2 + nf) * 2 + kk) * 64 + lane) * 8];
    __syncthreads();

    #pragma unroll
    for (int kk = 0; kk < 2; ++kk) {
      #pragma unroll
      for (int mf = 0; mf < 4; ++mf) {
        s16x8 af = *(const s16x8*)&Ab[(((wm * 4 + mf) * 2 + kk) * 64 + lane) * 8];
        #pragma unroll
        for (int nf = 0; nf < 2; ++nf)
          acc[mf][nf] = __builtin_amdgcn_mfma_f32_16x16x32_bf16(af, bfv[nf][kk], acc[mf][nf], 0, 0, 0);
      }
    }
  }

  const int l15 = lane & 15;
  const int lq = lane >> 4;
  #pragma unroll
  for (int nf = 0; nf < 2; ++nf) {
    const int col = n0 + wn * 32 + nf * 16 + l15;
    const float badd = bias[col] + skip_b[col];
    #pragma unroll
    for (int mf = 0; mf < 4; ++mf) {
      const int r0 = m0 + wm * 64 + mf * 16 + lq * 4;
      #pragma unroll
      for (int r = 0; r < 4; ++r)
        out[(size_t)(r0 + r) * W + col] = acc[mf][nf][r] + badd;
    }
  }
}

__global__ __launch_bounds__(256, 1) void ln_gelu(
    float* __restrict__ out, const float* __restrict__ gamma,
    const float* __restrict__ beta)
{
  const int lane = threadIdx.x & 63;
  const int wid = threadIdx.x >> 6;
  const int row = blockIdx.x * 4 + wid;
  float* p = out + (size_t)row * W + lane * 8;
  float4 a = *(const float4*)p;
  float4 b = *(const float4*)(p + 4);
  float v[8] = {a.x, a.y, a.z, a.w, b.x, b.y, b.z, b.w};
  float s = 0.f, q = 0.f;
  #pragma unroll
  for (int j = 0; j < 8; ++j) { s += v[j]; q += v[j] * v[j]; }
  #pragma unroll
  for (int m = 1; m < 64; m <<= 1) {
    s += __shfl_xor(s, m);
    q += __shfl_xor(q, m);
  }
  const float mu = s * (1.0f / 512.0f);
  const float var = q * (1.0f / 512.0f) - mu * mu;
  const float inv = rsqrtf(var + 1e-5f);
  const float4 g0 = *(const float4*)(gamma + lane * 8);
  const float4 g1 = *(const float4*)(gamma + lane * 8 + 4);
  const float4 b0 = *(const float4*)(beta + lane * 8);
  const float4 b1 = *(const float4*)(beta + lane * 8 + 4);
  float gm[8] = {g0.x, g0.y, g0.z, g0.w, g1.x, g1.y, g1.z, g1.w};
  float bt[8] = {b0.x, b0.y, b0.z, b0.w, b1.x, b1.y, b1.z, b1.w};
  float o[8];
  #pragma unroll
  for (int j = 0; j < 8; ++j) {
    float x = (v[j] - mu) * inv * gm[j] + bt[j];
    o[j] = 0.5f * x * (1.0f + erff(x * 0.70710678f));
  }
  float4 w0 = {o[0], o[1], o[2], o[3]};
  float4 w1 = {o[4], o[5], o[6], o[7]};
  *(float4*)p = w0;
  *(float4*)(p + 4) = w1;
}

extern "C" void kernel_launch(void* const* d_in, const int* in_sizes, int n_in,
                              void* d_out, int out_size, void* d_ws, size_t ws_size,
                              hipStream_t stream) {
  (void)in_sizes; (void)n_in; (void)out_size;
  const float* inp    = (const float*)d_in[0];
  const float* shift  = (const float*)d_in[1];
  const float* lscale = (const float*)d_in[2];
  const float* coeffs = (const float*)d_in[3];
  const float* bias   = (const float*)d_in[4];
  const float* skip_w = (const float*)d_in[5];
  const float* skip_b = (const float*)d_in[6];
  const float* gamma  = (const float*)d_in[7];
  const float* beta   = (const float*)d_in[8];
  float* out = (float*)d_out;

  const size_t needB = (size_t)NCHUNK * 4 * 16384;   // 8,650,752

  if (ws_size >= needB) {
    short* Bws = (short*)d_ws;
    bws_build<<<dim3(2112), dim3(256), 0, stream>>>(coeffs, skip_w, Bws);
    kan_gemm_v6<<<dim3(512), dim3(256), 0, stream>>>(
        inp, shift, lscale, Bws, bias, skip_b, out);
  } else {
    kan_gemm_v2<<<dim3(256), dim3(512), 0, stream>>>(
        inp, shift, lscale, coeffs, bias, skip_w, skip_b, out);
  }
  ln_gelu<<<dim3(BATCH / 4), dim3(256), 0, stream>>>(out, gamma, beta);
}